// Round 5
// baseline (475.534 us; speedup 1.0000x reference)
//
#include <hip/hip_runtime.h>

#define BATCH 16
#define CH    256
#define NPT   2048
#define DQK   32
#define OTOT  320   // 32 q + 32 k + 256 v
#define EPSB  1e-5f
#define SLOPE 0.2f

typedef __attribute__((ext_vector_type(8))) short bf16x8;
typedef __attribute__((ext_vector_type(4))) float f32x4;

__device__ __forceinline__ unsigned short f2bf(float f) {
    unsigned u = __float_as_uint(f);
    u = (u + 0x7FFFu + ((u >> 16) & 1u)) >> 16;
    return (unsigned short)u;
}
__device__ __forceinline__ float bf2f(unsigned short h) {
    return __uint_as_float(((unsigned)h) << 16);
}
__device__ __forceinline__ unsigned pack2(float a, float b) {
    return (unsigned)f2bf(a) | ((unsigned)f2bf(b) << 16);
}

// ---------------------------------------------------------------------------
// Kernel 0: split weights to Whi/Wlo bf16 [o][c] (A-frag layout) + bias Bv[o].
// grid 320 x 256.
__global__ __launch_bounds__(256) void prep_kernel(
    const float* __restrict__ qw, const float* __restrict__ qb,
    const float* __restrict__ kw, const float* __restrict__ kb,
    const float* __restrict__ vw, const float* __restrict__ vb,
    unsigned short* __restrict__ Whi, unsigned short* __restrict__ Wlo,
    float* __restrict__ Bv)
{
    int idx = blockIdx.x * 256 + threadIdx.x;   // < 81920
    int o = idx >> 8, c = idx & 255;
    float w;
    if (o < 32)      w = qw[(size_t)o * CH + c];
    else if (o < 64) w = kw[(size_t)(o - 32) * CH + c];
    else             w = vw[(size_t)(o - 64) * CH + c];
    unsigned short wh = f2bf(w);
    float rem = w - bf2f(wh);
    Whi[idx] = wh;
    Wlo[idx] = f2bf(rem);
    if (idx < OTOT) {
        int oo = idx;
        float bb;
        if (oo < 32)      bb = qb[oo];
        else if (oo < 64) bb = kb[oo - 32];
        else              bb = vb[oo - 64];
        Bv[oo] = bb;
    }
}

// ---------------------------------------------------------------------------
// Kernel 1: conv1x1 as bf16x3 MFMA GEMM (fp32-grade precision).
// Block: 64o x 128n for one b. grid (5, 16, 16), block 256 (waves 2o x 2n).
// Fused: bias, bf16 store, per-channel sum/sumsq atomics.
__global__ __launch_bounds__(256) void conv_kernel(
    const float* __restrict__ x,
    const unsigned short* __restrict__ Whi, const unsigned short* __restrict__ Wlo,
    const float* __restrict__ Bv,
    unsigned short* __restrict__ Ybf,
    float* __restrict__ Sum, float* __restrict__ Sq)
{
    int ob = blockIdx.x * 64;
    int n0 = blockIdx.y * 128;
    int b  = blockIdx.z;
    int tid = threadIdx.x;
    int w = tid >> 6, lane = tid & 63;
    int quad = lane >> 4, l16 = lane & 15;
    int wo = w >> 1, wn = w & 1;

    __shared__ unsigned short Xh[128][40];   // [n_local][c_local]
    __shared__ unsigned short Xl[128][40];

    int nl = tid & 127;       // n_local 0..127
    int ch = tid >> 7;        // c half: covers c_local = ch*16 .. +15
    const float* xb = x + (size_t)b * CH * NPT + n0 + nl;

    f32x4 acc[2][4];
#pragma unroll
    for (int ot = 0; ot < 2; ++ot)
#pragma unroll
        for (int nt = 0; nt < 4; ++nt)
            acc[ot][nt] = (f32x4){0.f, 0.f, 0.f, 0.f};

    float xv[16];
#pragma unroll
    for (int i = 0; i < 16; ++i)
        xv[i] = xb[(size_t)(ch * 16 + i) * NPT];

    for (int ks = 0; ks < 8; ++ks) {
        __syncthreads();
#pragma unroll
        for (int g = 0; g < 4; ++g) {
            ushort4 h4, l4;
            unsigned short* ph = (unsigned short*)&h4;
            unsigned short* pl = (unsigned short*)&l4;
#pragma unroll
            for (int j = 0; j < 4; ++j) {
                float f = xv[g * 4 + j];
                unsigned short h = f2bf(f);
                ph[j] = h;
                pl[j] = f2bf(f - bf2f(h));
            }
            *(ushort4*)&Xh[nl][ch * 16 + g * 4] = h4;
            *(ushort4*)&Xl[nl][ch * 16 + g * 4] = l4;
        }
        __syncthreads();

        if (ks < 7) {
#pragma unroll
            for (int i = 0; i < 16; ++i)
                xv[i] = xb[(size_t)((ks + 1) * 32 + ch * 16 + i) * NPT];
        }

        bf16x8 ah[2], al[2];
#pragma unroll
        for (int ot = 0; ot < 2; ++ot) {
            size_t orow = (size_t)(ob + wo * 32 + ot * 16 + l16) * 256 + ks * 32 + quad * 8;
            ah[ot] = *(const bf16x8*)(Whi + orow);
            al[ot] = *(const bf16x8*)(Wlo + orow);
        }
#pragma unroll
        for (int nt = 0; nt < 4; ++nt) {
            int nr = wn * 64 + nt * 16 + l16;
            bf16x8 bh = *(const bf16x8*)&Xh[nr][quad * 8];
            bf16x8 bl = *(const bf16x8*)&Xl[nr][quad * 8];
#pragma unroll
            for (int ot = 0; ot < 2; ++ot) {
                acc[ot][nt] = __builtin_amdgcn_mfma_f32_16x16x32_bf16(ah[ot], bh, acc[ot][nt], 0, 0, 0);
                acc[ot][nt] = __builtin_amdgcn_mfma_f32_16x16x32_bf16(ah[ot], bl, acc[ot][nt], 0, 0, 0);
                acc[ot][nt] = __builtin_amdgcn_mfma_f32_16x16x32_bf16(al[ot], bh, acc[ot][nt], 0, 0, 0);
            }
        }
    }

#pragma unroll
    for (int ot = 0; ot < 2; ++ot) {
        int obase = ob + wo * 32 + ot * 16 + quad * 4;
        float bias[4], sv[4], sq[4];
#pragma unroll
        for (int r = 0; r < 4; ++r) {
            bias[r] = Bv[obase + r];
            sv[r] = 0.f; sq[r] = 0.f;
        }
#pragma unroll
        for (int nt = 0; nt < 4; ++nt) {
            int n = n0 + wn * 64 + nt * 16 + l16;
#pragma unroll
            for (int r = 0; r < 4; ++r) {
                float v = acc[ot][nt][r] + bias[r];
                Ybf[((size_t)b * OTOT + obase + r) * NPT + n] = f2bf(v);
                sv[r] += v; sq[r] += v * v;
            }
        }
#pragma unroll
        for (int r = 0; r < 4; ++r) {
            float a = sv[r], q = sq[r];
            a += __shfl_xor(a, 1); q += __shfl_xor(q, 1);
            a += __shfl_xor(a, 2); q += __shfl_xor(q, 2);
            a += __shfl_xor(a, 4); q += __shfl_xor(q, 4);
            a += __shfl_xor(a, 8); q += __shfl_xor(q, 8);
            if (l16 == 0) {
                atomicAdd(&Sum[obase + r], a);
                atomicAdd(&Sq[obase + r], q);
            }
        }
    }
}

// ---------------------------------------------------------------------------
// Kernel 2: finalize BN affine: A[o], Cc[o].  1 block, 320 threads.
__global__ __launch_bounds__(320) void finalize_kernel(
    const float* __restrict__ Sum, const float* __restrict__ Sq,
    const float* __restrict__ qg, const float* __restrict__ qbe,
    const float* __restrict__ kg, const float* __restrict__ kbe,
    const float* __restrict__ vg, const float* __restrict__ vbe,
    float* __restrict__ A, float* __restrict__ Cc)
{
    int o = threadIdx.x;
    if (o >= OTOT) return;
    const float inv = 1.0f / (BATCH * NPT);
    float mean = Sum[o] * inv;
    float var  = Sq[o] * inv - mean * mean;
    float g, be;
    if (o < 32)      { g = qg[o];      be = qbe[o];      }
    else if (o < 64) { g = kg[o - 32]; be = kbe[o - 32]; }
    else             { g = vg[o - 64]; be = vbe[o - 64]; }
    float a = g * rsqrtf(var + EPSB);
    A[o]  = a;
    Cc[o] = be - mean * a;
}

// ---------------------------------------------------------------------------
// Kernel 3: pack pass — v: affine+LeakyReLU -> Vbf [b][c][n];
//                       q/k: affine + transpose -> QKt [b][n][64].
// grid (32, 16), block 256.
__global__ __launch_bounds__(256) void pack_kernel(
    const unsigned short* __restrict__ Ybf,
    const float* __restrict__ A, const float* __restrict__ Cc,
    unsigned short* __restrict__ QKt, unsigned short* __restrict__ Vbf)
{
    int b = blockIdx.y, n0 = blockIdx.x * 64;
    int tid = threadIdx.x;

    for (int e = tid; e < 4096; e += 256) {
        int c = e >> 4, n4 = (e & 15) * 4;
        ushort4 v4 = *(const ushort4*)(Ybf + ((size_t)b * OTOT + 64 + c) * NPT + n0 + n4);
        float a = A[64 + c], cc = Cc[64 + c];
        ushort4 w4;
        unsigned short* pi = (unsigned short*)&v4;
        unsigned short* po = (unsigned short*)&w4;
#pragma unroll
        for (int i = 0; i < 4; ++i) {
            float y = bf2f(pi[i]) * a + cc;
            y = (y > 0.f) ? y : SLOPE * y;
            po[i] = f2bf(y);
        }
        *(ushort4*)(Vbf + ((size_t)b * CH + c) * NPT + n0 + n4) = w4;
    }

    __shared__ unsigned short T[64][72];
    for (int e = tid; e < 1024; e += 256) {
        int o = e >> 4, n4 = (e & 15) * 4;
        ushort4 v4 = *(const ushort4*)(Ybf + ((size_t)b * OTOT + o) * NPT + n0 + n4);
        float a = A[o], cc = Cc[o];
        unsigned short* pi = (unsigned short*)&v4;
#pragma unroll
        for (int i = 0; i < 4; ++i)
            T[n4 + i][o] = f2bf(bf2f(pi[i]) * a + cc);
    }
    __syncthreads();
    for (int e = tid; e < 1024; e += 256) {
        int nn = e >> 4, o4 = (e & 15) * 4;
        ushort4 v4 = *(const ushort4*)&T[nn][o4];
        *(ushort4*)(QKt + ((size_t)b * NPT + n0 + nn) * 64 + o4) = v4;
    }
}

// ---------------------------------------------------------------------------
// Kernel 4: MFMA flash attention, register-resident P (no LDS, no barriers).
// grid 1024 (XCD-swizzled b,z,n0), block 256; wave w owns queries n0+w*16.
// S^T via mfma(A=K, B=Qt): C-frag (key=quad*4+r, query=l16) feeds PV B-frag
// (key=quad*8+j, query=l16) via 8 intra-wave bpermutes + 4 selects.
__global__ __launch_bounds__(256, 4) void attn_kernel(
    const unsigned short* __restrict__ QKt,
    const unsigned short* __restrict__ Vbf,
    const float* __restrict__ x,
    float* __restrict__ out)
{
    int L = blockIdx.x;
    int xcd = L & 7, k = L >> 3;
    int gi = k >> 5, n0i = k & 31;
    int grp = xcd * 4 + gi;           // 0..31
    int b = grp >> 1, z = grp & 1;
    int n0 = n0i * 64;

    int tid = threadIdx.x;
    int w = tid >> 6, lane = tid & 63;
    int quad = lane >> 4, l16 = lane & 15;

    const unsigned short* QK = QKt + (size_t)b * NPT * 64;
    const unsigned short* V  = Vbf + ((size_t)b * CH + z * 128) * NPT;

    // Q B-frag (resident): B[d=quad*8+j][n=l16] = QKt[b][n0+w*16+l16][quad*8+j]
    bf16x8 qf = *(const bf16x8*)(QK + ((size_t)(n0 + w * 16 + l16)) * 64 + quad * 8);

    f32x4 o[8];
#pragma unroll
    for (int ct = 0; ct < 8; ++ct) o[ct] = (f32x4){0.f, 0.f, 0.f, 0.f};
    float rsum = 0.f;

    const f32x4 zero4 = (f32x4){0.f, 0.f, 0.f, 0.f};
    const int sA = ((quad & 1) * 2) * 16 + l16;
    const int sB = sA + 16;
    const bool hiTile = quad >= 2;

    for (int m0 = 0; m0 < NPT; m0 += 32) {
        // K A-frags: A[m=l16][d=quad*8+j], keys m0..m0+15 and m0+16..m0+31
        bf16x8 kf0 = *(const bf16x8*)(QK + ((size_t)(m0 + l16)) * 64 + 32 + quad * 8);
        bf16x8 kf1 = *(const bf16x8*)(QK + ((size_t)(m0 + 16 + l16)) * 64 + 32 + quad * 8);

        f32x4 st0 = __builtin_amdgcn_mfma_f32_16x16x32_bf16(kf0, qf, zero4, 0, 0, 0);
        f32x4 st1 = __builtin_amdgcn_mfma_f32_16x16x32_bf16(kf1, qf, zero4, 0, 0, 0);

        // exp (max-free: |s| <= ~40 << 88) + fp32 row-sum + pack to bf16
        float p0 = __expf(st0[0]), p1 = __expf(st0[1]);
        float p2 = __expf(st0[2]), p3 = __expf(st0[3]);
        float q0 = __expf(st1[0]), q1 = __expf(st1[1]);
        float q2 = __expf(st1[2]), q3 = __expf(st1[3]);
        rsum += (p0 + p1) + (p2 + p3) + (q0 + q1) + (q2 + q3);

        unsigned t0pk0 = pack2(p0, p1), t0pk1 = pack2(p2, p3);
        unsigned t1pk0 = pack2(q0, q1), t1pk1 = pack2(q2, q3);

        // intra-wave permute: B-frag reg j pair <- source quad's packed pair
        unsigned a0 = __shfl(t0pk0, sA), b0 = __shfl(t1pk0, sA);
        unsigned a1 = __shfl(t0pk1, sA), b1 = __shfl(t1pk1, sA);
        unsigned a2 = __shfl(t0pk0, sB), b2 = __shfl(t1pk0, sB);
        unsigned a3 = __shfl(t0pk1, sB), b3 = __shfl(t1pk1, sB);
        union { unsigned u[4]; bf16x8 v; } pf;
        pf.u[0] = hiTile ? b0 : a0;
        pf.u[1] = hiTile ? b1 : a1;
        pf.u[2] = hiTile ? b2 : a2;
        pf.u[3] = hiTile ? b3 : a3;

        // PV: O[c][n] += V[c][m] * P^T[m][n], K=32 keys
#pragma unroll
        for (int ct = 0; ct < 8; ++ct) {
            bf16x8 vf = *(const bf16x8*)(V + ((size_t)(ct * 16 + l16)) * NPT + m0 + quad * 8);
            o[ct] = __builtin_amdgcn_mfma_f32_16x16x32_bf16(vf, pf.v, o[ct], 0, 0, 0);
        }
    }

    // total row-sum for query l16 (sum partials across quads)
    rsum += __shfl_xor(rsum, 16);
    rsum += __shfl_xor(rsum, 32);
    float rtot = 1.0f / rsum;

    // epilogue: scale + residual; lane holds c = z*128+ct*16+quad*4+r, n = n0+w*16+l16
    int n = n0 + w * 16 + l16;
#pragma unroll
    for (int ct = 0; ct < 8; ++ct) {
        int cbase = z * 128 + ct * 16 + quad * 4;
#pragma unroll
        for (int r = 0; r < 4; ++r) {
            size_t gidx = ((size_t)b * CH + cbase + r) * NPT + n;
            out[gidx] = o[ct][r] * rtot + x[gidx];
        }
    }
}

// ---------------------------------------------------------------------------
extern "C" void kernel_launch(void* const* d_in, const int* in_sizes, int n_in,
                              void* d_out, int out_size, void* d_ws, size_t ws_size,
                              hipStream_t stream)
{
    const float* x   = (const float*)d_in[0];
    const float* qw  = (const float*)d_in[1];
    const float* qb  = (const float*)d_in[2];
    const float* qg  = (const float*)d_in[3];
    const float* qbe = (const float*)d_in[4];
    const float* kw  = (const float*)d_in[5];
    const float* kb  = (const float*)d_in[6];
    const float* kg  = (const float*)d_in[7];
    const float* kbe = (const float*)d_in[8];
    const float* vw  = (const float*)d_in[9];
    const float* vb  = (const float*)d_in[10];
    const float* vg  = (const float*)d_in[11];
    const float* vbe = (const float*)d_in[12];
    float* out = (float*)d_out;

    unsigned short* Ybf = (unsigned short*)d_ws;
    unsigned short* QKt = Ybf + (size_t)BATCH * OTOT * NPT;          // 10,485,760 elems
    unsigned short* Vbf = QKt + (size_t)BATCH * NPT * 64;            // +2,097,152
    float* tail = (float*)(Vbf + (size_t)BATCH * CH * NPT);          // +8,388,608
    float* Sum = tail;
    float* Sq  = tail + OTOT;
    float* A   = tail + 2 * OTOT;
    float* Cc  = tail + 3 * OTOT;
    unsigned short* Whi = QKt;                         // overlay, consumed pre-pack
    unsigned short* Wlo = Whi + (size_t)CH * OTOT;
    float* Bv = (float*)(Wlo + (size_t)CH * OTOT);

    hipMemsetAsync(Sum, 0, 2 * OTOT * sizeof(float), stream);
    prep_kernel    <<<320, 256, 0, stream>>>(qw, qb, kw, kb, vw, vb, Whi, Wlo, Bv);
    conv_kernel    <<<dim3(5, 16, 16), 256, 0, stream>>>(x, Whi, Wlo, Bv, Ybf, Sum, Sq);
    finalize_kernel<<<1, 320, 0, stream>>>(Sum, Sq, qg, qbe, kg, kbe, vg, vbe, A, Cc);
    pack_kernel    <<<dim3(NPT / 64, BATCH), 256, 0, stream>>>(Ybf, A, Cc, QKt, Vbf);
    attn_kernel    <<<1024, 256, 0, stream>>>(QKt, Vbf, x, out);
}